// Round 1
// baseline (457.627 us; speedup 1.0000x reference)
//
#include <hip/hip_runtime.h>

#define H 16
#define DK 64

// ---------------------------------------------------------------------------
// Kernel 1: per (b,h) precompute
//   R_K[e] = sum_d R[b,h,d]*WK_w[e,d] + WK_b[e]
//   R_V[e] = sum_d R[b,h,d]*WV_w[e,d] + WV_b[e]
//   u[d]   = sum_e WQ_w[e,d]*R_K[e]           (WQ folded into the gate)
//   c      = sum_e WQ_b[e]*R_K[e]
// grid = dps*H blocks of 64 threads; negligible runtime.
// ---------------------------------------------------------------------------
__global__ __launch_bounds__(64) void prep_kernel(
    const float* __restrict__ R,
    const float* __restrict__ WQ_w, const float* __restrict__ WQ_b,
    const float* __restrict__ WK_w, const float* __restrict__ WK_b,
    const float* __restrict__ WV_w, const float* __restrict__ WV_b,
    float* __restrict__ u, float* __restrict__ rv, float* __restrict__ c) {
    const int bh = blockIdx.x;           // b*H + h
    const int e  = threadIdx.x;          // 0..63
    __shared__ float r_s[DK];
    __shared__ float rk_s[DK];

    r_s[e] = R[bh * DK + e];             // R is (dps,1,H*DK) contiguous
    __syncthreads();

    float rk  = WK_b[e];
    float rvv = WV_b[e];
#pragma unroll
    for (int d = 0; d < DK; ++d) {
        rk  += r_s[d] * WK_w[e * DK + d];
        rvv += r_s[d] * WV_w[e * DK + d];
    }
    rk_s[e] = rk;
    rv[bh * DK + e] = rvv;
    __syncthreads();

    // u[d] for d = e
    float uu = 0.f;
#pragma unroll
    for (int ee = 0; ee < DK; ++ee) uu += WQ_w[ee * DK + e] * rk_s[ee];
    u[bh * DK + e] = uu;

    if (e == 0) {
        float cc = 0.f;
        for (int ee = 0; ee < DK; ++ee) cc += WQ_b[ee] * rk_s[ee];
        c[bh] = cc;
    }
}

// ---------------------------------------------------------------------------
// Kernel 2: streaming pass over S.
// Block = 256 threads handles ROWS_PER_BLOCK consecutive rows of one batch.
// Thread t owns columns [4t, 4t+4) of the 1024-wide row -> head h = t/16,
// within-head float4 index (t&15). u4/rv4 are loop-invariant registers.
// Per-head dot: 4x __shfl_xor across the 16 lanes of the head group.
// ---------------------------------------------------------------------------
#define ROWS_PER_BLOCK 16

__global__ __launch_bounds__(256) void fused_kernel(
    const float* __restrict__ S, const int* __restrict__ S_mas,
    const float* __restrict__ u, const float* __restrict__ rv,
    const float* __restrict__ c, float* __restrict__ out,
    int seq_len, int blocks_per_batch) {
    const int t = threadIdx.x;
    const int h = t >> 4;                          // head 0..15
    const int b = blockIdx.x / blocks_per_batch;
    const int srow0 = (blockIdx.x % blocks_per_batch) * ROWS_PER_BLOCK;
    const int d_model = H * DK;                    // 1024

    const int bh = b * H + h;
    const float4 u4  = *(const float4*)(u  + bh * DK + (t & 15) * 4);
    const float4 rv4 = *(const float4*)(rv + bh * DK + (t & 15) * 4);
    const float  ch  = c[bh];

    const size_t base = (size_t)b * seq_len * d_model + (size_t)srow0 * d_model + t * 4;
    const float* srow = S + base;
    float*       orow = out + base;
    const int*   mrow = S_mas + (size_t)b * seq_len + srow0;

#pragma unroll 4
    for (int r = 0; r < ROWS_PER_BLOCK; ++r) {
        float4 s4 = *(const float4*)(srow + (size_t)r * d_model);
        float p = s4.x * u4.x + s4.y * u4.y + s4.z * u4.z + s4.w * u4.w;
        p += __shfl_xor(p, 1);
        p += __shfl_xor(p, 2);
        p += __shfl_xor(p, 4);
        p += __shfl_xor(p, 8);
        const float beta = p + ch;
        const int m = mrow[r];
        float4 o4;
        if (m != 0) {
            o4.x = rv4.x * beta; o4.y = rv4.y * beta;
            o4.z = rv4.z * beta; o4.w = rv4.w * beta;
        } else {
            o4.x = 0.f; o4.y = 0.f; o4.z = 0.f; o4.w = 0.f;
        }
        *(float4*)(orow + (size_t)r * d_model) = o4;
    }
}

extern "C" void kernel_launch(void* const* d_in, const int* in_sizes, int n_in,
                              void* d_out, int out_size, void* d_ws, size_t ws_size,
                              hipStream_t stream) {
    const float* S     = (const float*)d_in[0];
    const float* R     = (const float*)d_in[1];
    const int*   S_mas = (const int*)d_in[2];
    // d_in[3] = R_mas (dead in reference output)
    const float* WQ_w  = (const float*)d_in[4];
    const float* WQ_b  = (const float*)d_in[5];
    const float* WK_w  = (const float*)d_in[6];
    const float* WK_b  = (const float*)d_in[7];
    const float* WV_w  = (const float*)d_in[8];
    const float* WV_b  = (const float*)d_in[9];
    float* out = (float*)d_out;

    const int d_model = H * DK;                      // 1024
    const int dps     = in_sizes[1] / d_model;       // 32
    const int seq_len = in_sizes[0] / (dps * d_model); // 2048

    float* u_ws  = (float*)d_ws;                     // dps*H*DK floats
    float* rv_ws = u_ws + (size_t)dps * H * DK;      // dps*H*DK floats
    float* c_ws  = rv_ws + (size_t)dps * H * DK;     // dps*H floats

    prep_kernel<<<dps * H, 64, 0, stream>>>(R, WQ_w, WQ_b, WK_w, WK_b, WV_w, WV_b,
                                            u_ws, rv_ws, c_ws);

    const int blocks_per_batch = seq_len / ROWS_PER_BLOCK;   // 128
    fused_kernel<<<dps * blocks_per_batch, 256, 0, stream>>>(
        S, S_mas, u_ws, rv_ws, c_ws, out, seq_len, blocks_per_batch);
}

// Round 2
// 437.092 us; speedup vs baseline: 1.0470x; 1.0470x over previous
//
#include <hip/hip_runtime.h>

#define H 16
#define DK 64

// ---------------------------------------------------------------------------
// Kernel 1: per (b,h) precompute
//   R_K[e] = sum_d R[b,h,d]*WK_w[e,d] + WK_b[e]
//   R_V[e] = sum_d R[b,h,d]*WV_w[e,d] + WV_b[e]
//   u[d]   = sum_e WQ_w[e,d]*R_K[e]           (WQ folded into the gate)
//   c      = sum_e WQ_b[e]*R_K[e]
// grid = dps*H blocks of 64 threads; negligible runtime.
// ---------------------------------------------------------------------------
__global__ __launch_bounds__(64) void prep_kernel(
    const float* __restrict__ R,
    const float* __restrict__ WQ_w, const float* __restrict__ WQ_b,
    const float* __restrict__ WK_w, const float* __restrict__ WK_b,
    const float* __restrict__ WV_w, const float* __restrict__ WV_b,
    float* __restrict__ u, float* __restrict__ rv, float* __restrict__ c) {
    const int bh = blockIdx.x;           // b*H + h
    const int e  = threadIdx.x;          // 0..63
    __shared__ float r_s[DK];
    __shared__ float rk_s[DK];

    r_s[e] = R[bh * DK + e];             // R is (dps,1,H*DK) contiguous
    __syncthreads();

    float rk  = WK_b[e];
    float rvv = WV_b[e];
#pragma unroll
    for (int d = 0; d < DK; ++d) {
        rk  += r_s[d] * WK_w[e * DK + d];
        rvv += r_s[d] * WV_w[e * DK + d];
    }
    rk_s[e] = rk;
    rv[bh * DK + e] = rvv;
    __syncthreads();

    // u[d] for d = e
    float uu = 0.f;
#pragma unroll
    for (int ee = 0; ee < DK; ++ee) uu += WQ_w[ee * DK + e] * rk_s[ee];
    u[bh * DK + e] = uu;

    if (e == 0) {
        float cc = 0.f;
        for (int ee = 0; ee < DK; ++ee) cc += WQ_b[ee] * rk_s[ee];
        c[bh] = cc;
    }
}

// ---------------------------------------------------------------------------
// Kernel 2: streaming pass over S.
// Block = 256 threads handles ROWS_PER_BLOCK consecutive rows of one batch.
// Thread t owns columns [4t, 4t+4) of the 1024-wide row -> head h = t/16,
// within-head float4 index (t&15). u4/rv4 are loop-invariant registers.
// Per-head dot: 4x __shfl_xor across the 16 lanes of the head group.
// Masked rows (mask==0): output zero WITHOUT reading S -- wave-uniform skip
// halves the average HBM fetch.
// ---------------------------------------------------------------------------
#define ROWS_PER_BLOCK 16

__global__ __launch_bounds__(256) void fused_kernel(
    const float* __restrict__ S, const int* __restrict__ S_mas,
    const float* __restrict__ u, const float* __restrict__ rv,
    const float* __restrict__ c, float* __restrict__ out,
    int seq_len, int blocks_per_batch) {
    const int t = threadIdx.x;
    const int h = t >> 4;                          // head 0..15
    const int b = blockIdx.x / blocks_per_batch;
    const int srow0 = (blockIdx.x % blocks_per_batch) * ROWS_PER_BLOCK;
    const int d_model = H * DK;                    // 1024

    const int bh = b * H + h;
    const float4 u4  = *(const float4*)(u  + bh * DK + (t & 15) * 4);
    const float4 rv4 = *(const float4*)(rv + bh * DK + (t & 15) * 4);
    const float  ch  = c[bh];

    const size_t base = (size_t)b * seq_len * d_model + (size_t)srow0 * d_model + t * 4;
    const float* srow = S + base;
    float*       orow = out + base;
    const int*   mrow = S_mas + (size_t)b * seq_len + srow0;

    // Hoist all mask loads so their latency overlaps and the per-row branch
    // doesn't serialize on a fresh load each iteration.
    int m[ROWS_PER_BLOCK];
#pragma unroll
    for (int r = 0; r < ROWS_PER_BLOCK; ++r) m[r] = mrow[r];

#pragma unroll 4
    for (int r = 0; r < ROWS_PER_BLOCK; ++r) {
        float4 o4;
        if (m[r] != 0) {                           // block-uniform branch
            float4 s4 = *(const float4*)(srow + (size_t)r * d_model);
            float p = s4.x * u4.x + s4.y * u4.y + s4.z * u4.z + s4.w * u4.w;
            p += __shfl_xor(p, 1);
            p += __shfl_xor(p, 2);
            p += __shfl_xor(p, 4);
            p += __shfl_xor(p, 8);
            const float beta = p + ch;
            o4.x = rv4.x * beta; o4.y = rv4.y * beta;
            o4.z = rv4.z * beta; o4.w = rv4.w * beta;
        } else {
            o4.x = 0.f; o4.y = 0.f; o4.z = 0.f; o4.w = 0.f;
        }
        *(float4*)(orow + (size_t)r * d_model) = o4;
    }
}

extern "C" void kernel_launch(void* const* d_in, const int* in_sizes, int n_in,
                              void* d_out, int out_size, void* d_ws, size_t ws_size,
                              hipStream_t stream) {
    const float* S     = (const float*)d_in[0];
    const float* R     = (const float*)d_in[1];
    const int*   S_mas = (const int*)d_in[2];
    // d_in[3] = R_mas (dead in reference output)
    const float* WQ_w  = (const float*)d_in[4];
    const float* WQ_b  = (const float*)d_in[5];
    const float* WK_w  = (const float*)d_in[6];
    const float* WK_b  = (const float*)d_in[7];
    const float* WV_w  = (const float*)d_in[8];
    const float* WV_b  = (const float*)d_in[9];
    float* out = (float*)d_out;

    const int d_model = H * DK;                      // 1024
    const int dps     = in_sizes[1] / d_model;       // 32
    const int seq_len = in_sizes[0] / (dps * d_model); // 2048

    float* u_ws  = (float*)d_ws;                     // dps*H*DK floats
    float* rv_ws = u_ws + (size_t)dps * H * DK;      // dps*H*DK floats
    float* c_ws  = rv_ws + (size_t)dps * H * DK;     // dps*H floats

    prep_kernel<<<dps * H, 64, 0, stream>>>(R, WQ_w, WQ_b, WK_w, WK_b, WV_w, WV_b,
                                            u_ws, rv_ws, c_ws);

    const int blocks_per_batch = seq_len / ROWS_PER_BLOCK;   // 128
    fused_kernel<<<dps * blocks_per_batch, 256, 0, stream>>>(
        S, S_mas, u_ws, rv_ws, c_ws, out, seq_len, blocks_per_batch);
}

// Round 4
// 431.359 us; speedup vs baseline: 1.0609x; 1.0133x over previous
//
#include <hip/hip_runtime.h>

#define H 16
#define DK 64

typedef float vfloat4 __attribute__((ext_vector_type(4)));  // clang-native for nontemporal builtins

// ---------------------------------------------------------------------------
// Kernel 1: per (b,h) precompute
//   R_K[e] = sum_d R[b,h,d]*WK_w[e,d] + WK_b[e]
//   R_V[e] = sum_d R[b,h,d]*WV_w[e,d] + WV_b[e]
//   u[d]   = sum_e WQ_w[e,d]*R_K[e]           (WQ folded into the gate)
//   c      = sum_e WQ_b[e]*R_K[e]
// grid = dps*H blocks of 64 threads; negligible runtime.
// ---------------------------------------------------------------------------
__global__ __launch_bounds__(64) void prep_kernel(
    const float* __restrict__ R,
    const float* __restrict__ WQ_w, const float* __restrict__ WQ_b,
    const float* __restrict__ WK_w, const float* __restrict__ WK_b,
    const float* __restrict__ WV_w, const float* __restrict__ WV_b,
    float* __restrict__ u, float* __restrict__ rv, float* __restrict__ c) {
    const int bh = blockIdx.x;           // b*H + h
    const int e  = threadIdx.x;          // 0..63
    __shared__ float r_s[DK];
    __shared__ float rk_s[DK];

    r_s[e] = R[bh * DK + e];             // R is (dps,1,H*DK) contiguous
    __syncthreads();

    float rk  = WK_b[e];
    float rvv = WV_b[e];
#pragma unroll
    for (int d = 0; d < DK; ++d) {
        rk  += r_s[d] * WK_w[e * DK + d];
        rvv += r_s[d] * WV_w[e * DK + d];
    }
    rk_s[e] = rk;
    rv[bh * DK + e] = rvv;
    __syncthreads();

    // u[d] for d = e
    float uu = 0.f;
#pragma unroll
    for (int ee = 0; ee < DK; ++ee) uu += WQ_w[ee * DK + e] * rk_s[ee];
    u[bh * DK + e] = uu;

    if (e == 0) {
        float cc = 0.f;
        for (int ee = 0; ee < DK; ++ee) cc += WQ_b[ee] * rk_s[ee];
        c[bh] = cc;
    }
}

// ---------------------------------------------------------------------------
// Kernel 2: streaming pass over S.
// Block = 256 threads handles ROWS_PER_BLOCK consecutive rows of one batch.
// Thread t owns columns [4t, 4t+4) of the 1024-wide row -> head h = t/16,
// within-head float4 index (t&15). u4/rv4 are loop-invariant registers.
// Per-head dot: 4x __shfl_xor across the 16 lanes of the head group.
// Masked rows: zero output WITHOUT reading S (block-uniform skip).
// Non-temporal load/store on the two big streams (S, out): each byte is
// touched exactly once -> bypass L2 pollution.
// ---------------------------------------------------------------------------
#define ROWS_PER_BLOCK 16

__global__ __launch_bounds__(256) void fused_kernel(
    const float* __restrict__ S, const int* __restrict__ S_mas,
    const float* __restrict__ u, const float* __restrict__ rv,
    const float* __restrict__ c, float* __restrict__ out,
    int seq_len, int blocks_per_batch) {
    const int t = threadIdx.x;
    const int h = t >> 4;                          // head 0..15
    const int b = blockIdx.x / blocks_per_batch;
    const int srow0 = (blockIdx.x % blocks_per_batch) * ROWS_PER_BLOCK;
    const int d_model = H * DK;                    // 1024

    const int bh = b * H + h;
    const vfloat4 u4  = *(const vfloat4*)(u  + bh * DK + (t & 15) * 4);
    const vfloat4 rv4 = *(const vfloat4*)(rv + bh * DK + (t & 15) * 4);
    const float   ch  = c[bh];

    const size_t base = (size_t)b * seq_len * d_model + (size_t)srow0 * d_model + t * 4;
    const float* srow = S + base;
    float*       orow = out + base;
    const int*   mrow = S_mas + (size_t)b * seq_len + srow0;

    // Hoist all mask loads so their latency overlaps.
    int m[ROWS_PER_BLOCK];
#pragma unroll
    for (int r = 0; r < ROWS_PER_BLOCK; ++r) m[r] = mrow[r];

#pragma unroll
    for (int r = 0; r < ROWS_PER_BLOCK; ++r) {
        vfloat4 o4;
        if (m[r] != 0) {                           // block-uniform branch
            const vfloat4 s4 =
                __builtin_nontemporal_load((const vfloat4*)(srow + (size_t)r * d_model));
            float p = s4.x * u4.x + s4.y * u4.y + s4.z * u4.z + s4.w * u4.w;
            p += __shfl_xor(p, 1);
            p += __shfl_xor(p, 2);
            p += __shfl_xor(p, 4);
            p += __shfl_xor(p, 8);
            const float beta = p + ch;
            o4.x = rv4.x * beta; o4.y = rv4.y * beta;
            o4.z = rv4.z * beta; o4.w = rv4.w * beta;
        } else {
            o4 = (vfloat4)(0.f);
        }
        __builtin_nontemporal_store(o4, (vfloat4*)(orow + (size_t)r * d_model));
    }
}

extern "C" void kernel_launch(void* const* d_in, const int* in_sizes, int n_in,
                              void* d_out, int out_size, void* d_ws, size_t ws_size,
                              hipStream_t stream) {
    const float* S     = (const float*)d_in[0];
    const float* R     = (const float*)d_in[1];
    const int*   S_mas = (const int*)d_in[2];
    // d_in[3] = R_mas (dead in reference output)
    const float* WQ_w  = (const float*)d_in[4];
    const float* WQ_b  = (const float*)d_in[5];
    const float* WK_w  = (const float*)d_in[6];
    const float* WK_b  = (const float*)d_in[7];
    const float* WV_w  = (const float*)d_in[8];
    const float* WV_b  = (const float*)d_in[9];
    float* out = (float*)d_out;

    const int d_model = H * DK;                      // 1024
    const int dps     = in_sizes[1] / d_model;       // 32
    const int seq_len = in_sizes[0] / (dps * d_model); // 2048

    float* u_ws  = (float*)d_ws;                     // dps*H*DK floats
    float* rv_ws = u_ws + (size_t)dps * H * DK;      // dps*H*DK floats
    float* c_ws  = rv_ws + (size_t)dps * H * DK;     // dps*H floats

    prep_kernel<<<dps * H, 64, 0, stream>>>(R, WQ_w, WQ_b, WK_w, WK_b, WV_w, WV_b,
                                            u_ws, rv_ws, c_ws);

    const int blocks_per_batch = seq_len / ROWS_PER_BLOCK;   // 128
    fused_kernel<<<dps * blocks_per_batch, 256, 0, stream>>>(
        S, S_mas, u_ws, rv_ws, c_ws, out, seq_len, blocks_per_batch);
}